// Round 18
// baseline (507.429 us; speedup 1.0000x reference)
//
#include <hip/hip_runtime.h>
#include <math.h>

// Problem constants (B=4, S=1024, HIDDEN=4096, H=32, KV=8, D=128)
#define SEQ    1024
#define BATCH  4
#define MROWS  4096          // B*S
#define HID    4096
#define NHEADS 32
#define NKV    8
#define HDIM   128

typedef __bf16 bf16x8 __attribute__((ext_vector_type(8)));
typedef float  f32x4  __attribute__((ext_vector_type(4)));
typedef float  f32x16 __attribute__((ext_vector_type(16)));
typedef unsigned short u16x8 __attribute__((ext_vector_type(8)));
typedef unsigned short u16x4 __attribute__((ext_vector_type(4)));
typedef unsigned int   u32x4 __attribute__((ext_vector_type(4)));

static __device__ __forceinline__ unsigned short f2bf(float f) {
  union { float f; unsigned u; } x; x.f = f;
  unsigned r = x.u + 0x7fffu + ((x.u >> 16) & 1u);   // RNE
  return (unsigned short)(r >> 16);
}
static __device__ __forceinline__ float bf2f(unsigned short h) {
  union { unsigned u; float f; } x; x.u = ((unsigned)h) << 16;
  return x.f;
}
static __device__ __forceinline__ unsigned cvtpk_bf16(float lo, float hi) {
  unsigned r;
  asm("v_cvt_pk_bf16_f32 %0, %1, %2" : "=v"(r) : "v"(lo), "v"(hi));
  return r;
}

// async global->LDS, 16B per lane; LDS dest is wave-uniform base + lane*16
static __device__ __forceinline__ void gload16(const unsigned short* g, unsigned short* l) {
  __builtin_amdgcn_global_load_lds(
      (const __attribute__((address_space(1))) unsigned int*)g,
      (__attribute__((address_space(3))) unsigned int*)l, 16, 0, 0);
}

// ------------------------------------------------- fused f32 -> bf16 (all 5 inputs)
__global__ __launch_bounds__(256) void cvt_all(const float* __restrict__ hs,
                                               const float* __restrict__ wq,
                                               const float* __restrict__ wk,
                                               const float* __restrict__ wv,
                                               const float* __restrict__ wo,
                                               unsigned short* __restrict__ hs_b,
                                               unsigned short* __restrict__ wq_b,
                                               unsigned short* __restrict__ wk_b,
                                               unsigned short* __restrict__ wv_b,
                                               unsigned short* __restrict__ wo_b) {
  const int bid = blockIdx.x;
  const float* in; unsigned short* out; int base;
  if (bid < 8192)       { in = hs; out = hs_b; base = 0; }
  else if (bid < 16384) { in = wq; out = wq_b; base = 8192; }
  else if (bid < 18432) { in = wk; out = wk_b; base = 16384; }
  else if (bid < 20480) { in = wv; out = wv_b; base = 18432; }
  else                  { in = wo; out = wo_b; base = 20480; }
  const int i = (bid - base) * 256 + threadIdx.x;
  f32x4 a = ((const f32x4*)in)[2 * i];
  f32x4 b = ((const f32x4*)in)[2 * i + 1];
  u16x8 o;
  o[0] = f2bf(a[0]); o[1] = f2bf(a[1]); o[2] = f2bf(a[2]); o[3] = f2bf(a[3]);
  o[4] = f2bf(b[0]); o[5] = f2bf(b[1]); o[6] = f2bf(b[2]); o[7] = f2bf(b[3]);
  ((u16x8*)out)[i] = o;
}

// ---------------------------------------- fused K-proj + V-proj (128² tile GEMM)
// z=0: K = hs·wk^T -> bf16 [4096][1024]
// z=1: V = hs·wv^T -> swizzled V tiles [b][kv][kt32][d128][k32]
__global__ __launch_bounds__(256) void gemm_kv(const unsigned short* __restrict__ A,
                                               const unsigned short* __restrict__ Bk,
                                               const unsigned short* __restrict__ Bv,
                                               unsigned short* __restrict__ Ck,
                                               unsigned short* __restrict__ Cv) {
  __shared__ unsigned short As[4096];      // [128][32]
  __shared__ unsigned short Bs[4096];
  __shared__ unsigned short bounce[16384]; // 32KB C bounce
  const int t  = threadIdx.x;
  const int l  = t & 63, w = t >> 6;
  const int wr = w >> 1, wc = w & 1;
  const int lr = l & 15, lg = l >> 4;
  const int m0 = blockIdx.x * 128, n0 = blockIdx.y * 128;
  const int z  = blockIdx.z;
  const unsigned short* B = z ? Bv : Bk;
  const int K = 4096;

  const int srow = t >> 2;
  const int skg  = (t & 3) ^ (srow & 3);
  const unsigned short* ga0 = A + (long)(m0 + srow) * K + skg * 8;
  const unsigned short* ga1 = ga0 + 64L * K;
  const unsigned short* gb0 = B + (long)(n0 + srow) * K + skg * 8;
  const unsigned short* gb1 = gb0 + 64L * K;

  int aro[4], bro[4];
#pragma unroll
  for (int i = 0; i < 4; ++i) {
    aro[i] = (wr * 64 + i * 16 + lr) * 32 + ((lg ^ (lr & 3)) * 8);
    bro[i] = (wc * 64 + i * 16 + lr) * 32 + ((lg ^ (lr & 3)) * 8);
  }

  f32x4 acc[4][4] = {};
  for (int k0 = 0; k0 < K; k0 += 32) {
    if (k0) __syncthreads();
    gload16(ga0 + k0, As + (w << 9));
    gload16(ga1 + k0, As + 2048 + (w << 9));
    gload16(gb0 + k0, Bs + (w << 9));
    gload16(gb1 + k0, Bs + 2048 + (w << 9));
    __syncthreads();
    bf16x8 af[4], bfv[4];
#pragma unroll
    for (int i = 0; i < 4; ++i) af[i]  = *(const bf16x8*)(As + aro[i]);
#pragma unroll
    for (int i = 0; i < 4; ++i) bfv[i] = *(const bf16x8*)(Bs + bro[i]);
#pragma unroll
    for (int mi = 0; mi < 4; ++mi)
#pragma unroll
      for (int ni = 0; ni < 4; ++ni)
        acc[mi][ni] = __builtin_amdgcn_mfma_f32_16x16x32_bf16(af[mi], bfv[ni],
                                                              acc[mi][ni], 0, 0, 0);
  }

  const int rl0 = wr * 64 + lg * 4;        // local row base
  const int cl0 = wc * 64 + lr;            // local col base
  if (z == 0) {
    // K: bounce as [128][128] u16, then stream rows (256B segments)
#pragma unroll
    for (int mi = 0; mi < 4; ++mi)
#pragma unroll
      for (int ni = 0; ni < 4; ++ni)
#pragma unroll
        for (int j = 0; j < 4; ++j)
          bounce[(rl0 + mi * 16 + j) * 128 + (cl0 + ni * 16)] = f2bf(acc[mi][ni][j]);
    __syncthreads();
#pragma unroll
    for (int i = 0; i < 8; ++i) {
      const int o = i * 2048 + t * 8;
      *(u16x8*)(Ck + (long)(m0 + (o >> 7)) * 1024 + n0 + (o & 127)) =
          *(const u16x8*)(bounce + o);
    }
  } else {
    // V: bounce holds the block's 32KB contiguous V-tile region, then stream.
    const int bb      = m0 >> 10;
    const int kt_base = (m0 & 1023) >> 5;
    const int kvh     = n0 >> 7;
    const long base0  = ((long)((bb * NKV + kvh) * 32 + kt_base)) * 4096;
#pragma unroll
    for (int mi = 0; mi < 4; ++mi)
#pragma unroll
      for (int ni = 0; ni < 4; ++ni) {
        const int s_l   = rl0 + mi * 16;         // 0..127 (j adds 0..3)
        const int d_loc = cl0 + ni * 16;         // 0..127
        const int kt_l  = s_l >> 5;
        const int k_loc = s_l & 31;              // ≡0 mod 4
        const int fxor  = (d_loc ^ (d_loc >> 2)) & 3;
        const int off   = kt_l * 4096 + d_loc * 32 +
                          (((k_loc >> 3) ^ fxor) << 3) + (k_loc & 7);
        u16x4 v;
#pragma unroll
        for (int j = 0; j < 4; ++j) v[j] = f2bf(acc[mi][ni][j]);
        *(u16x4*)(bounce + off) = v;
      }
    __syncthreads();
#pragma unroll
    for (int i = 0; i < 8; ++i) {
      const int o = i * 2048 + t * 8;
      *(u16x8*)(Cv + base0 + o) = *(const u16x8*)(bounce + o);
    }
  }
}

// ---------------------------------------------- 256² 8-phase GEMM (T2+T3+T4+T5)
#define BAR8 __builtin_amdgcn_s_barrier()
#define WL0  do { asm volatile("s_waitcnt lgkmcnt(0)" ::: "memory"); \
                  __builtin_amdgcn_sched_barrier(0); } while (0)
#define WL8  asm volatile("s_waitcnt lgkmcnt(8)" ::: "memory")
#define WV6  asm volatile("s_waitcnt vmcnt(6)" ::: "memory")

template <int OUTMODE>
__global__ __launch_bounds__(512, 2) void gemm8_bt(const unsigned short* __restrict__ A,
                                                   const unsigned short* __restrict__ B,
                                                   void* __restrict__ Cp) {
  __shared__ unsigned short lds[65536];        // 128 KiB
  const int t = threadIdx.x, l = t & 63, w = t >> 6;
  const int wr = w >> 2, wc = w & 3;
  const int lr = l & 15, lg = l >> 4;
  const int bid = blockIdx.x;
  const int swz = (bid & 7) * 32 + (bid >> 3);  // XCD swizzle (256 % 8 == 0)
  const int m0 = (swz >> 4) << 8, n0 = (swz & 15) << 8;
  const long K = 4096;

  const int rc = l >> 3;
  const int ce = ((l & 7) ^ rc) << 3;

#define STGA(d, h, tt) do { \
    const unsigned short* _s = A + (long)(m0 + (h)*128 + w*8 + rc) * K + (long)(tt)*64 + ce; \
    gload16(_s,            lds + ((d)*2+(h))*8192 + w*512); \
    gload16(_s + 64L * K,  lds + ((d)*2+(h))*8192 + (8 + w)*512); \
  } while (0)
#define STGB(d, h, tt) do { \
    const unsigned short* _s = B + (long)(n0 + (h)*128 + w*8 + rc) * K + (long)(tt)*64 + ce; \
    gload16(_s,            lds + 32768 + ((d)*2+(h))*8192 + w*512); \
    gload16(_s + 64L * K,  lds + 32768 + ((d)*2+(h))*8192 + (8 + w)*512); \
  } while (0)
#define LDA8(d, rh) do { \
    _Pragma("unroll") for (int ri = 0; ri < 4; ++ri) \
    _Pragma("unroll") for (int kk = 0; kk < 2; ++kk) { \
      int r  = wr*64 + ri*16 + lr; \
      int cb = (kk*64 + lg*16) ^ ((l & 7) << 4); \
      a[ri][kk] = *(const bf16x8*)(lds + ((d)*2+(rh))*8192 + r*64 + (cb >> 1)); \
    } } while (0)
#define LDB8(d, ch, barr) do { \
    _Pragma("unroll") for (int ci = 0; ci < 2; ++ci) \
    _Pragma("unroll") for (int kk = 0; kk < 2; ++kk) { \
      int r  = wc*32 + ci*16 + lr; \
      int cb = (kk*64 + lg*16) ^ ((l & 7) << 4); \
      barr[ci][kk] = *(const bf16x8*)(lds + 32768 + ((d)*2+(ch))*8192 + r*64 + (cb >> 1)); \
    } } while (0)
#define MM8(rh, ch, barr) do { \
    __builtin_amdgcn_s_setprio(1); \
    _Pragma("unroll") for (int kk = 0; kk < 2; ++kk) \
    _Pragma("unroll") for (int ri = 0; ri < 4; ++ri) \
    _Pragma("unroll") for (int ci = 0; ci < 2; ++ci) \
      acc[rh][ch][ri][ci] = __builtin_amdgcn_mfma_f32_16x16x32_bf16( \
          a[ri][kk], barr[ci][kk], acc[rh][ch][ri][ci], 0, 0, 0); \
    __builtin_amdgcn_s_setprio(0); \
  } while (0)

  f32x4 acc[2][2][4][2] = {};
  bf16x8 a[4][2], b0[2][2], b1[2][2];

  STGA(0, 0, 0); STGB(0, 0, 0); STGB(0, 1, 0); STGA(0, 1, 0);
  STGA(1, 0, 1); STGB(1, 0, 1); STGB(1, 1, 1);
  WV6;
  BAR8;

  for (int i = 0; i < 32; ++i) {
    const int t1 = 2 * i + 1, t2 = (2 * i + 2) & 63, t3 = (2 * i + 3) & 63;
    LDA8(0, 0); LDB8(0, 0, b0);
    STGA(1, 1, t1);
    WL8;
    BAR8; WL0; MM8(0, 0, b0); BAR8;
    LDB8(0, 1, b1);
    STGA(0, 0, t2);
    BAR8; WL0; MM8(0, 1, b1); BAR8;
    LDA8(0, 1);
    STGB(0, 0, t2);
    BAR8; WL0; MM8(1, 1, b1); BAR8;
    STGB(0, 1, t2);
    WV6;
    BAR8; WL0; MM8(1, 0, b0); BAR8;
    LDA8(1, 0); LDB8(1, 0, b0);
    STGA(0, 1, t2);
    WL8;
    BAR8; WL0; MM8(0, 0, b0); BAR8;
    LDB8(1, 1, b1);
    STGA(1, 0, t3);
    BAR8; WL0; MM8(0, 1, b1); BAR8;
    LDA8(1, 1);
    STGB(1, 0, t3);
    BAR8; WL0; MM8(1, 1, b1); BAR8;
    STGB(1, 1, t3);
    WV6;
    BAR8; WL0; MM8(1, 0, b0); BAR8;
  }

  if (OUTMODE == 0) {
    // drain tail-stage DMAs still targeting lds, then reuse it as C bounce
    asm volatile("s_waitcnt vmcnt(0)" ::: "memory");
    __builtin_amdgcn_s_barrier();
#pragma unroll
    for (int rh = 0; rh < 2; ++rh)
#pragma unroll
      for (int ch = 0; ch < 2; ++ch)
#pragma unroll
        for (int ri = 0; ri < 4; ++ri)
#pragma unroll
          for (int ci = 0; ci < 2; ++ci)
#pragma unroll
            for (int j = 0; j < 4; ++j)
              lds[(rh * 128 + wr * 64 + ri * 16 + lg * 4 + j) * 256 +
                  ch * 128 + wc * 32 + ci * 16 + lr] = f2bf(acc[rh][ch][ri][ci][j]);
    __syncthreads();
#pragma unroll
    for (int i = 0; i < 16; ++i) {
      const int o = i * 4096 + t * 8;
      *(u16x8*)((unsigned short*)Cp + (long)(m0 + (o >> 8)) * 4096 + n0 + (o & 255)) =
          *(const u16x8*)(lds + o);
    }
  } else {
#pragma unroll
    for (int rh = 0; rh < 2; ++rh)
#pragma unroll
      for (int ch = 0; ch < 2; ++ch)
#pragma unroll
        for (int ri = 0; ri < 4; ++ri)
#pragma unroll
          for (int ci = 0; ci < 2; ++ci)
#pragma unroll
            for (int j = 0; j < 4; ++j) {
              const int row = m0 + rh * 128 + wr * 64 + ri * 16 + lg * 4 + j;
              const int col = n0 + ch * 128 + wc * 32 + ci * 16 + lr;
              ((float*)Cp)[(long)row * 4096 + col] = acc[rh][ch][ri][ci][j];
            }
  }
#undef STGA
#undef STGB
#undef LDA8
#undef LDB8
#undef MM8
}

// --------------------------------------------- per-head RMSNorm + RoPE (K only;
// Q's norm+rope is fused into attn_kernel's Q-hoist)
__global__ __launch_bounds__(256) void normrope_k(unsigned short* __restrict__ Kx,
                                                  const float* __restrict__ kwn,
                                                  const int* __restrict__ positions) {
  const int t = threadIdx.x, l = t & 63, wv = t >> 6;
  const int slice = blockIdx.x * 4 + wv;
  const int head  = slice & 7;
  const int row   = slice >> 3;
  const int s     = row & (SEQ - 1);
  unsigned short* p = Kx + (long)row * 1024 + (head << 7);

  float x1 = bf2f(p[l]), x2 = bf2f(p[l + 64]);
  float ss = x1 * x1 + x2 * x2;
#pragma unroll
  for (int m = 1; m < 64; m <<= 1) ss += __shfl_xor(ss, m, 64);
  float inv = rsqrtf(ss * (1.0f / 128.0f) + 1e-6f);
  x1 *= inv * kwn[l];
  x2 *= inv * kwn[l + 64];

  float invf = exp2f((float)l * -0.31143075889569023f);
  float ang  = (float)positions[s] * invf;
  float sn, cs;
  sincosf(ang, &sn, &cs);
  p[l]      = f2bf(x1 * cs - x2 * sn);
  p[l + 64] = f2bf(x2 * cs + x1 * sn);
}

// ------------------------------------------------------------ flash attention
// R9 ring-4 config (best measured) + fused Q RMSNorm+RoPE in the Q-hoist:
// lane l holds q-row lq=l&31 elements d=16ks+8hi+j; RoPE partner d+64 is
// raw[ks+4][j] (same lane); RMS reduce = one shfl_xor(32) (lanes l,l^32 share
// lq). Raw Q loads issued BEFORE the stage DMAs so consuming them (in-order
// vmcnt retirement) leaves all 12 stage DMAs in flight -> norm/rope VALU
// hides under prologue DMA latency.
__global__ __launch_bounds__(256, 2) void attn_kernel(const unsigned short* __restrict__ Q,
                                                      const unsigned short* __restrict__ Kb,
                                                      const unsigned short* __restrict__ Vtl,
                                                      const float* __restrict__ qwn,
                                                      const int* __restrict__ positions,
                                                      unsigned short* __restrict__ O) {
  __shared__ unsigned short lds[32768];   // 64 KiB: K rings [0,16384), V rings [16384,32768)
  __shared__ float cl[4][32];
  const int t = threadIdx.x, l = t & 63, w = t >> 6;
  const int lq = l & 31, hi = l >> 5;
  const int orig = blockIdx.x;
  const int blk = (orig & 7) * 128 + (orig >> 3);   // XCD swizzle (1024 % 8 == 0)
  const int qb = blk & 7, h = (blk >> 3) & 31, b = blk >> 8;
  const int kv = h >> 2;                     // GQA: 4 q-heads per kv-head
  const int q0 = qb * 128 + w * 32;

  const unsigned short* Kg = Kb + (long)(b * SEQ) * 1024 + kv * HDIM;
  const unsigned short* Vg = Vtl + (long)(b * NKV + kv) * 32 * 4096;

#define STG_K(ring, ti) do { \
    _Pragma("unroll") for (int rr = 0; rr < 2; ++rr) { \
      int _row = (rr * 4 + w) * 4 + (l >> 4); \
      int _sc  = (l & 15) ^ (_row & 15); \
      gload16(Kg + (long)((ti) * 32 + _row) * 1024 + (_sc << 3), \
              lds + (ring) * 4096 + (rr * 4 + w) * 512); \
    } } while (0)
#define STG_V(ring, ti) do { \
    _Pragma("unroll") for (int rr = 0; rr < 2; ++rr) \
      gload16(Vg + (long)(ti) * 4096 + (((rr * 4 + w) * 64 + l) << 3), \
              lds + 16384 + (ring) * 4096 + (rr * 4 + w) * 512); \
    } while (0)
#define QKT(dst, ring) do { \
    const unsigned short* kb = lds + (ring) * 4096 + lq * 128; \
    bf16x8 kf[8]; \
    _Pragma("unroll") for (int ks = 0; ks < 8; ++ks) \
      kf[ks] = *(const bf16x8*)(kb + ((((ks << 1) + hi) ^ (lq & 15)) << 3)); \
    __builtin_amdgcn_s_setprio(1); \
    _Pragma("unroll") for (int ks = 0; ks < 8; ++ks) \
      dst = __builtin_amdgcn_mfma_f32_32x32x16_bf16(kf[ks], qf[ks], dst, 0, 0, 0); \
    __builtin_amdgcn_s_setprio(0); \
  } while (0)

  // (1) raw Q loads first (oldest in VMEM queue)
  const int s_pos = q0 + lq;                 // position index (s_pos < SEQ)
  const unsigned short* qrow = Q + (long)(b * SEQ + s_pos) * HID + h * HDIM + 8 * hi;
  u16x8 raw[8];
#pragma unroll
  for (int ks = 0; ks < 8; ++ks) raw[ks] = *(const u16x8*)(qrow + ks * 16);

  // (2) stage tiles 0,1,2 (12 DMAs, stay in flight across Q math)
  STG_K(0, 0); STG_V(0, 0);
  STG_K(1, 1); STG_V(1, 1);
  STG_K(2, 2); STG_V(2, 2);

  // (3) fused RMSNorm (+weight) then RoPE then scale, all in registers
  const float qsc = 0.12751791438584222f;    // (1/sqrt(128)) * log2(e)
  const float posf = (float)positions[s_pos];
  float ss = 0.f;
#pragma unroll
  for (int ks = 0; ks < 8; ++ks)
#pragma unroll
    for (int j = 0; j < 8; ++j) { float x = bf2f(raw[ks][j]); ss += x * x; }
  ss += __shfl_xor(ss, 32, 64);
  const float innorm = rsqrtf(ss * (1.0f / 128.0f) + 1e-6f);

  bf16x8 qf[8];
#pragma unroll
  for (int ks = 0; ks < 4; ++ks) {
    bf16x8 qlo, qhi;
#pragma unroll
    for (int j = 0; j < 8; ++j) {
      const int d = 16 * ks + 8 * hi + j;    // in [0,64)
      float sn, cs;
      sincosf(posf * exp2f((float)d * -0.31143075889569023f), &sn, &cs);
      const float xa = bf2f(raw[ks][j])     * innorm * qwn[d];
      const float xb = bf2f(raw[ks + 4][j]) * innorm * qwn[d + 64];
      qlo[j] = (__bf16)((xa * cs - xb * sn) * qsc);
      qhi[j] = (__bf16)((xb * cs + xa * sn) * qsc);
    }
    qf[ks] = qlo; qf[ks + 4] = qhi;
  }

  f32x16 acc[4] = {};
  float m = -3.0e38f, lsum = 0.f;

  // tile0 landed (12 DMA outstanding -> 8 leaves oldest 4 done)
  asm volatile("s_waitcnt vmcnt(8)" ::: "memory");
  __builtin_amdgcn_s_barrier();
  __builtin_amdgcn_sched_barrier(0);

  f32x16 s_cur = {};
  QKT(s_cur, 0);

#pragma unroll 2
  for (int ti = 0; ti < 32; ++ti) {
    asm volatile("s_waitcnt vmcnt(4)" ::: "memory");
    __builtin_amdgcn_s_barrier();
    __builtin_amdgcn_sched_barrier(0);

    const int rs = (ti + 3) & 3, tn = (ti + 3) & 31;
    STG_K(rs, tn); STG_V(rs, tn);

    // QK^T of NEXT tile (independent of softmax below)
    f32x16 s_next = {};
    QKT(s_next, (ti + 1) & 3);

    // online softmax on s_cur (tile ti)
    float t0 = fmaxf(fmaxf(s_cur[0], s_cur[1]), fmaxf(s_cur[2], s_cur[3]));
    float t1 = fmaxf(fmaxf(s_cur[4], s_cur[5]), fmaxf(s_cur[6], s_cur[7]));
    float t2 = fmaxf(fmaxf(s_cur[8], s_cur[9]), fmaxf(s_cur[10], s_cur[11]));
    float t3 = fmaxf(fmaxf(s_cur[12], s_cur[13]), fmaxf(s_cur[14], s_cur[15]));
    float rm = fmaxf(fmaxf(t0, t1), fmaxf(t2, t3));
    rm = fmaxf(rm, __shfl_xor(rm, 32, 64));

    if (__any(rm > m + 8.0f)) {        // T13 defer-max
      float mn = fmaxf(m, rm);
      float corr = exp2f(m - mn);
      m = mn;
      lsum *= corr;
      cl[w][lq] = corr;
      float cc[16];
#pragma unroll
      for (int r = 0; r < 16; ++r)
        cc[r] = cl[w][(r & 3) + 8 * (r >> 2) + 4 * hi];
#pragma unroll
      for (int db = 0; db < 4; ++db)
#pragma unroll
        for (int r = 0; r < 16; ++r) acc[db][r] *= cc[r];
    }

    float p[16];
    float ps = 0.f;
#pragma unroll
    for (int r = 0; r < 16; ++r) { p[r] = exp2f(s_cur[r] - m); ps += p[r]; }
    lsum += ps + __shfl_xor(ps, 32, 64);

    // T12: pack P into PV A-fragments
    bf16x8 pa[2];
#pragma unroll
    for (int c = 0; c < 2; ++c) {
      unsigned a0 = cvtpk_bf16(p[8 * c + 0], p[8 * c + 1]);
      unsigned b0 = cvtpk_bf16(p[8 * c + 4], p[8 * c + 5]);
      unsigned a1 = cvtpk_bf16(p[8 * c + 2], p[8 * c + 3]);
      unsigned b1 = cvtpk_bf16(p[8 * c + 6], p[8 * c + 7]);
      asm("v_permlane32_swap_b32 %0, %1" : "+v"(a0), "+v"(b0));
      asm("v_permlane32_swap_b32 %0, %1" : "+v"(a1), "+v"(b1));
      u32x4 w4 = {a0, a1, b0, b1};
      pa[c] = __builtin_bit_cast(bf16x8, w4);
    }

    // PV from V ring ti&3 (swizzled [d][k32] tile)
    __builtin_amdgcn_s_setprio(1);
#pragma unroll
    for (int db = 0; db < 4; ++db) {
      const int row = db * 32 + lq;
      const int fx  = (row ^ (row >> 2)) & 3;
      const unsigned short* vb = lds + 16384 + (ti & 3) * 4096 + row * 32;
      bf16x8 v0 = *(const bf16x8*)(vb + ((hi ^ fx) << 3));
      bf16x8 v1 = *(const bf16x8*)(vb + (((2 + hi) ^ fx) << 3));
      acc[db] = __builtin_amdgcn_mfma_f32_32x32x16_bf16(pa[0], v0, acc[db], 0, 0, 0);
      acc[db] = __builtin_amdgcn_mfma_f32_32x32x16_bf16(pa[1], v1, acc[db], 0, 0, 0);
    }
    __builtin_amdgcn_s_setprio(0);

    s_cur = s_next;
  }
#undef STG_K
#undef STG_V
#undef QKT

  float il = 1.0f / lsum;
  cl[w][lq] = il;
  float ic[16];
#pragma unroll
  for (int r = 0; r < 16; ++r)
    ic[r] = cl[w][(r & 3) + 8 * (r >> 2) + 4 * hi];
#pragma unroll
  for (int db = 0; db < 4; ++db)
#pragma unroll
    for (int r = 0; r < 16; ++r) {
      int row = (r & 3) + 8 * (r >> 2) + 4 * hi;
      O[(long)(b * SEQ + q0 + row) * HID + h * HDIM + db * 32 + lq] =
          f2bf(acc[db][r] * ic[r]);
    }
}

// ------------------------------------------------------------------- launcher
extern "C" void kernel_launch(void* const* d_in, const int* in_sizes, int n_in,
                              void* d_out, int out_size, void* d_ws, size_t ws_size,
                              hipStream_t stream) {
  (void)in_sizes; (void)n_in; (void)out_size; (void)ws_size;
  const int*   positions = (const int*)d_in[0];
  const float* hs = (const float*)d_in[1];
  const float* wq = (const float*)d_in[2];
  const float* wk = (const float*)d_in[3];
  const float* wv = (const float*)d_in[4];
  const float* wo = (const float*)d_in[5];
  const float* qw = (const float*)d_in[6];
  const float* kw = (const float*)d_in[7];

  char* ws = (char*)d_ws;                                   // 160 MB total
  unsigned short* hs_b = (unsigned short*)(ws);              // 32 MB
  unsigned short* wq_b = (unsigned short*)(ws + 33554432);   // 32 MB (reused as attn-out)
  unsigned short* wk_b = (unsigned short*)(ws + 67108864);   //  8 MB
  unsigned short* wv_b = (unsigned short*)(ws + 75497472);   //  8 MB
  unsigned short* wo_b = (unsigned short*)(ws + 83886080);   // 32 MB
  unsigned short* q_b  = (unsigned short*)(ws + 117440512);  // 32 MB
  unsigned short* k_b  = (unsigned short*)(ws + 150994944);  //  8 MB
  unsigned short* vt_b = (unsigned short*)(ws + 159383552);  //  8 MB (V tiles)
  unsigned short* ao_b = wq_b;  // wq dead after Q-proj; alias for attention out

  // fused f32 -> bf16 conversion (5 segments, one launch)
  cvt_all<<<dim3(28672), dim3(256), 0, stream>>>(hs, wq, wk, wv, wo,
                                                 hs_b, wq_b, wk_b, wv_b, wo_b);

  // Q-proj (8-phase 256²) then fused K+V proj (z-indexed)
  gemm8_bt<0><<<dim3(256), dim3(512), 0, stream>>>(hs_b, wq_b, q_b);
  gemm_kv<<<dim3(32, 8, 2), dim3(256), 0, stream>>>(hs_b, wk_b, wv_b, k_b, vt_b);

  // RMSNorm + RoPE for K only (Q's is fused into attention)
  normrope_k<<<dim3(8192), dim3(256), 0, stream>>>(k_b, kw, positions);

  // attention: 1024 x 256-thread blocks, ring-4 pipelined K/V, fused Q-norm/rope
  attn_kernel<<<dim3(1024), dim3(256), 0, stream>>>(q_b, k_b, vt_b, qw, positions, ao_b);

  // output projection -> f32 d_out (8-phase 256² template)
  gemm8_bt<1><<<dim3(256), dim3(512), 0, stream>>>(ao_b, wo_b, (float*)d_out);
}

// Round 19
// 497.069 us; speedup vs baseline: 1.0208x; 1.0208x over previous
//
#include <hip/hip_runtime.h>
#include <math.h>

// Problem constants (B=4, S=1024, HIDDEN=4096, H=32, KV=8, D=128)
#define SEQ    1024
#define BATCH  4
#define MROWS  4096          // B*S
#define HID    4096
#define NHEADS 32
#define NKV    8
#define HDIM   128

typedef __bf16 bf16x8 __attribute__((ext_vector_type(8)));
typedef float  f32x4  __attribute__((ext_vector_type(4)));
typedef float  f32x16 __attribute__((ext_vector_type(16)));
typedef unsigned short u16x8 __attribute__((ext_vector_type(8)));
typedef unsigned short u16x4 __attribute__((ext_vector_type(4)));
typedef unsigned int   u32x4 __attribute__((ext_vector_type(4)));

static __device__ __forceinline__ unsigned short f2bf(float f) {
  union { float f; unsigned u; } x; x.f = f;
  unsigned r = x.u + 0x7fffu + ((x.u >> 16) & 1u);   // RNE
  return (unsigned short)(r >> 16);
}
static __device__ __forceinline__ float bf2f(unsigned short h) {
  union { unsigned u; float f; } x; x.u = ((unsigned)h) << 16;
  return x.f;
}
static __device__ __forceinline__ unsigned cvtpk_bf16(float lo, float hi) {
  unsigned r;
  asm("v_cvt_pk_bf16_f32 %0, %1, %2" : "=v"(r) : "v"(lo), "v"(hi));
  return r;
}

// async global->LDS, 16B per lane; LDS dest is wave-uniform base + lane*16
static __device__ __forceinline__ void gload16(const unsigned short* g, unsigned short* l) {
  __builtin_amdgcn_global_load_lds(
      (const __attribute__((address_space(1))) unsigned int*)g,
      (__attribute__((address_space(3))) unsigned int*)l, 16, 0, 0);
}

// ------------------------------------------------- fused f32 -> bf16 (all 5 inputs)
__global__ __launch_bounds__(256) void cvt_all(const float* __restrict__ hs,
                                               const float* __restrict__ wq,
                                               const float* __restrict__ wk,
                                               const float* __restrict__ wv,
                                               const float* __restrict__ wo,
                                               unsigned short* __restrict__ hs_b,
                                               unsigned short* __restrict__ wq_b,
                                               unsigned short* __restrict__ wk_b,
                                               unsigned short* __restrict__ wv_b,
                                               unsigned short* __restrict__ wo_b) {
  const int bid = blockIdx.x;
  const float* in; unsigned short* out; int base;
  if (bid < 8192)       { in = hs; out = hs_b; base = 0; }
  else if (bid < 16384) { in = wq; out = wq_b; base = 8192; }
  else if (bid < 18432) { in = wk; out = wk_b; base = 16384; }
  else if (bid < 20480) { in = wv; out = wv_b; base = 18432; }
  else                  { in = wo; out = wo_b; base = 20480; }
  const int i = (bid - base) * 256 + threadIdx.x;
  f32x4 a = ((const f32x4*)in)[2 * i];
  f32x4 b = ((const f32x4*)in)[2 * i + 1];
  u16x8 o;
  o[0] = f2bf(a[0]); o[1] = f2bf(a[1]); o[2] = f2bf(a[2]); o[3] = f2bf(a[3]);
  o[4] = f2bf(b[0]); o[5] = f2bf(b[1]); o[6] = f2bf(b[2]); o[7] = f2bf(b[3]);
  ((u16x8*)out)[i] = o;
}

// ---------------------------------------- fused K-proj + V-proj (128² tile GEMM)
// z=0: K = hs·wk^T -> bf16 [4096][1024]
// z=1: V = hs·wv^T -> swizzled V tiles [b][kv][kt32][d128][k32]
__global__ __launch_bounds__(256) void gemm_kv(const unsigned short* __restrict__ A,
                                               const unsigned short* __restrict__ Bk,
                                               const unsigned short* __restrict__ Bv,
                                               unsigned short* __restrict__ Ck,
                                               unsigned short* __restrict__ Cv) {
  __shared__ unsigned short As[4096];      // [128][32]
  __shared__ unsigned short Bs[4096];
  __shared__ unsigned short bounce[16384]; // 32KB C bounce
  const int t  = threadIdx.x;
  const int l  = t & 63, w = t >> 6;
  const int wr = w >> 1, wc = w & 1;
  const int lr = l & 15, lg = l >> 4;
  const int m0 = blockIdx.x * 128, n0 = blockIdx.y * 128;
  const int z  = blockIdx.z;
  const unsigned short* B = z ? Bv : Bk;
  const int K = 4096;

  const int srow = t >> 2;
  const int skg  = (t & 3) ^ (srow & 3);
  const unsigned short* ga0 = A + (long)(m0 + srow) * K + skg * 8;
  const unsigned short* ga1 = ga0 + 64L * K;
  const unsigned short* gb0 = B + (long)(n0 + srow) * K + skg * 8;
  const unsigned short* gb1 = gb0 + 64L * K;

  int aro[4], bro[4];
#pragma unroll
  for (int i = 0; i < 4; ++i) {
    aro[i] = (wr * 64 + i * 16 + lr) * 32 + ((lg ^ (lr & 3)) * 8);
    bro[i] = (wc * 64 + i * 16 + lr) * 32 + ((lg ^ (lr & 3)) * 8);
  }

  f32x4 acc[4][4] = {};
  for (int k0 = 0; k0 < K; k0 += 32) {
    if (k0) __syncthreads();
    gload16(ga0 + k0, As + (w << 9));
    gload16(ga1 + k0, As + 2048 + (w << 9));
    gload16(gb0 + k0, Bs + (w << 9));
    gload16(gb1 + k0, Bs + 2048 + (w << 9));
    __syncthreads();
    bf16x8 af[4], bfv[4];
#pragma unroll
    for (int i = 0; i < 4; ++i) af[i]  = *(const bf16x8*)(As + aro[i]);
#pragma unroll
    for (int i = 0; i < 4; ++i) bfv[i] = *(const bf16x8*)(Bs + bro[i]);
#pragma unroll
    for (int mi = 0; mi < 4; ++mi)
#pragma unroll
      for (int ni = 0; ni < 4; ++ni)
        acc[mi][ni] = __builtin_amdgcn_mfma_f32_16x16x32_bf16(af[mi], bfv[ni],
                                                              acc[mi][ni], 0, 0, 0);
  }

  const int rl0 = wr * 64 + lg * 4;        // local row base
  const int cl0 = wc * 64 + lr;            // local col base
  if (z == 0) {
    // K: bounce as [128][128] u16, then stream rows (256B segments)
#pragma unroll
    for (int mi = 0; mi < 4; ++mi)
#pragma unroll
      for (int ni = 0; ni < 4; ++ni)
#pragma unroll
        for (int j = 0; j < 4; ++j)
          bounce[(rl0 + mi * 16 + j) * 128 + (cl0 + ni * 16)] = f2bf(acc[mi][ni][j]);
    __syncthreads();
#pragma unroll
    for (int i = 0; i < 8; ++i) {
      const int o = i * 2048 + t * 8;
      *(u16x8*)(Ck + (long)(m0 + (o >> 7)) * 1024 + n0 + (o & 127)) =
          *(const u16x8*)(bounce + o);
    }
  } else {
    // V: bounce holds the block's 32KB contiguous V-tile region, then stream.
    const int bb      = m0 >> 10;
    const int kt_base = (m0 & 1023) >> 5;
    const int kvh     = n0 >> 7;
    const long base0  = ((long)((bb * NKV + kvh) * 32 + kt_base)) * 4096;
#pragma unroll
    for (int mi = 0; mi < 4; ++mi)
#pragma unroll
      for (int ni = 0; ni < 4; ++ni) {
        const int s_l   = rl0 + mi * 16;         // 0..127 (j adds 0..3)
        const int d_loc = cl0 + ni * 16;         // 0..127
        const int kt_l  = s_l >> 5;
        const int k_loc = s_l & 31;              // ≡0 mod 4
        const int fxor  = (d_loc ^ (d_loc >> 2)) & 3;
        const int off   = kt_l * 4096 + d_loc * 32 +
                          (((k_loc >> 3) ^ fxor) << 3) + (k_loc & 7);
        u16x4 v;
#pragma unroll
        for (int j = 0; j < 4; ++j) v[j] = f2bf(acc[mi][ni][j]);
        *(u16x4*)(bounce + off) = v;
      }
    __syncthreads();
#pragma unroll
    for (int i = 0; i < 8; ++i) {
      const int o = i * 2048 + t * 8;
      *(u16x8*)(Cv + base0 + o) = *(const u16x8*)(bounce + o);
    }
  }
}

// ---------------------------------------------- 256² 8-phase GEMM (T2+T3+T4+T5)
#define BAR8 __builtin_amdgcn_s_barrier()
#define WL0  do { asm volatile("s_waitcnt lgkmcnt(0)" ::: "memory"); \
                  __builtin_amdgcn_sched_barrier(0); } while (0)
#define WL8  asm volatile("s_waitcnt lgkmcnt(8)" ::: "memory")
#define WV6  asm volatile("s_waitcnt vmcnt(6)" ::: "memory")

template <int OUTMODE>
__global__ __launch_bounds__(512, 2) void gemm8_bt(const unsigned short* __restrict__ A,
                                                   const unsigned short* __restrict__ B,
                                                   void* __restrict__ Cp) {
  __shared__ unsigned short lds[65536];        // 128 KiB
  const int t = threadIdx.x, l = t & 63, w = t >> 6;
  const int wr = w >> 2, wc = w & 3;
  const int lr = l & 15, lg = l >> 4;
  const int bid = blockIdx.x;
  const int swz = (bid & 7) * 32 + (bid >> 3);  // XCD swizzle (256 % 8 == 0)
  const int m0 = (swz >> 4) << 8, n0 = (swz & 15) << 8;
  const long K = 4096;

  const int rc = l >> 3;
  const int ce = ((l & 7) ^ rc) << 3;

#define STGA(d, h, tt) do { \
    const unsigned short* _s = A + (long)(m0 + (h)*128 + w*8 + rc) * K + (long)(tt)*64 + ce; \
    gload16(_s,            lds + ((d)*2+(h))*8192 + w*512); \
    gload16(_s + 64L * K,  lds + ((d)*2+(h))*8192 + (8 + w)*512); \
  } while (0)
#define STGB(d, h, tt) do { \
    const unsigned short* _s = B + (long)(n0 + (h)*128 + w*8 + rc) * K + (long)(tt)*64 + ce; \
    gload16(_s,            lds + 32768 + ((d)*2+(h))*8192 + w*512); \
    gload16(_s + 64L * K,  lds + 32768 + ((d)*2+(h))*8192 + (8 + w)*512); \
  } while (0)
#define LDA8(d, rh) do { \
    _Pragma("unroll") for (int ri = 0; ri < 4; ++ri) \
    _Pragma("unroll") for (int kk = 0; kk < 2; ++kk) { \
      int r  = wr*64 + ri*16 + lr; \
      int cb = (kk*64 + lg*16) ^ ((l & 7) << 4); \
      a[ri][kk] = *(const bf16x8*)(lds + ((d)*2+(rh))*8192 + r*64 + (cb >> 1)); \
    } } while (0)
#define LDB8(d, ch, barr) do { \
    _Pragma("unroll") for (int ci = 0; ci < 2; ++ci) \
    _Pragma("unroll") for (int kk = 0; kk < 2; ++kk) { \
      int r  = wc*32 + ci*16 + lr; \
      int cb = (kk*64 + lg*16) ^ ((l & 7) << 4); \
      barr[ci][kk] = *(const bf16x8*)(lds + 32768 + ((d)*2+(ch))*8192 + r*64 + (cb >> 1)); \
    } } while (0)
#define MM8(rh, ch, barr) do { \
    __builtin_amdgcn_s_setprio(1); \
    _Pragma("unroll") for (int kk = 0; kk < 2; ++kk) \
    _Pragma("unroll") for (int ri = 0; ri < 4; ++ri) \
    _Pragma("unroll") for (int ci = 0; ci < 2; ++ci) \
      acc[rh][ch][ri][ci] = __builtin_amdgcn_mfma_f32_16x16x32_bf16( \
          a[ri][kk], barr[ci][kk], acc[rh][ch][ri][ci], 0, 0, 0); \
    __builtin_amdgcn_s_setprio(0); \
  } while (0)

  f32x4 acc[2][2][4][2] = {};
  bf16x8 a[4][2], b0[2][2], b1[2][2];

  STGA(0, 0, 0); STGB(0, 0, 0); STGB(0, 1, 0); STGA(0, 1, 0);
  STGA(1, 0, 1); STGB(1, 0, 1); STGB(1, 1, 1);
  WV6;
  BAR8;

  for (int i = 0; i < 32; ++i) {
    const int t1 = 2 * i + 1, t2 = (2 * i + 2) & 63, t3 = (2 * i + 3) & 63;
    LDA8(0, 0); LDB8(0, 0, b0);
    STGA(1, 1, t1);
    WL8;
    BAR8; WL0; MM8(0, 0, b0); BAR8;
    LDB8(0, 1, b1);
    STGA(0, 0, t2);
    BAR8; WL0; MM8(0, 1, b1); BAR8;
    LDA8(0, 1);
    STGB(0, 0, t2);
    BAR8; WL0; MM8(1, 1, b1); BAR8;
    STGB(0, 1, t2);
    WV6;
    BAR8; WL0; MM8(1, 0, b0); BAR8;
    LDA8(1, 0); LDB8(1, 0, b0);
    STGA(0, 1, t2);
    WL8;
    BAR8; WL0; MM8(0, 0, b0); BAR8;
    LDB8(1, 1, b1);
    STGA(1, 0, t3);
    BAR8; WL0; MM8(0, 1, b1); BAR8;
    LDA8(1, 1);
    STGB(1, 0, t3);
    BAR8; WL0; MM8(1, 1, b1); BAR8;
    STGB(1, 1, t3);
    WV6;
    BAR8; WL0; MM8(1, 0, b0); BAR8;
  }

  if (OUTMODE == 0) {
    // drain tail-stage DMAs still targeting lds, then reuse it as C bounce
    asm volatile("s_waitcnt vmcnt(0)" ::: "memory");
    __builtin_amdgcn_s_barrier();
#pragma unroll
    for (int rh = 0; rh < 2; ++rh)
#pragma unroll
      for (int ch = 0; ch < 2; ++ch)
#pragma unroll
        for (int ri = 0; ri < 4; ++ri)
#pragma unroll
          for (int ci = 0; ci < 2; ++ci)
#pragma unroll
            for (int j = 0; j < 4; ++j)
              lds[(rh * 128 + wr * 64 + ri * 16 + lg * 4 + j) * 256 +
                  ch * 128 + wc * 32 + ci * 16 + lr] = f2bf(acc[rh][ch][ri][ci][j]);
    __syncthreads();
#pragma unroll
    for (int i = 0; i < 16; ++i) {
      const int o = i * 4096 + t * 8;
      *(u16x8*)((unsigned short*)Cp + (long)(m0 + (o >> 8)) * 4096 + n0 + (o & 255)) =
          *(const u16x8*)(lds + o);
    }
  } else {
#pragma unroll
    for (int rh = 0; rh < 2; ++rh)
#pragma unroll
      for (int ch = 0; ch < 2; ++ch)
#pragma unroll
        for (int ri = 0; ri < 4; ++ri)
#pragma unroll
          for (int ci = 0; ci < 2; ++ci)
#pragma unroll
            for (int j = 0; j < 4; ++j) {
              const int row = m0 + rh * 128 + wr * 64 + ri * 16 + lg * 4 + j;
              const int col = n0 + ch * 128 + wc * 32 + ci * 16 + lr;
              ((float*)Cp)[(long)row * 4096 + col] = acc[rh][ch][ri][ci][j];
            }
  }
#undef STGA
#undef STGB
#undef LDA8
#undef LDB8
#undef MM8
}

// --------------------------------- fused per-head RMSNorm + RoPE (Q and K in one)
__global__ __launch_bounds__(256) void normrope_all(unsigned short* __restrict__ Qx,
                                                    unsigned short* __restrict__ Kx,
                                                    const float* __restrict__ qwn,
                                                    const float* __restrict__ kwn,
                                                    const int* __restrict__ positions) {
  const int t = threadIdx.x, l = t & 63, wv = t >> 6;
  const int bid = blockIdx.x;
  unsigned short* X; const float* wnorm; int hshift, stride, slice;
  if (bid < 32768) { X = Qx; wnorm = qwn; hshift = 5; stride = 4096; slice = bid * 4 + wv; }
  else             { X = Kx; wnorm = kwn; hshift = 3; stride = 1024; slice = (bid - 32768) * 4 + wv; }
  const int head  = slice & ((1 << hshift) - 1);
  const int row   = slice >> hshift;
  const int s     = row & (SEQ - 1);
  unsigned short* p = X + (long)row * stride + (head << 7);

  float x1 = bf2f(p[l]), x2 = bf2f(p[l + 64]);
  float ss = x1 * x1 + x2 * x2;
#pragma unroll
  for (int m = 1; m < 64; m <<= 1) ss += __shfl_xor(ss, m, 64);
  float inv = rsqrtf(ss * (1.0f / 128.0f) + 1e-6f);
  x1 *= inv * wnorm[l];
  x2 *= inv * wnorm[l + 64];

  float invf = exp2f((float)l * -0.31143075889569023f);
  float ang  = (float)positions[s] * invf;
  float sn, cs;
  sincosf(ang, &sn, &cs);
  p[l]      = f2bf(x1 * cs - x2 * sn);
  p[l + 64] = f2bf(x2 * cs + x1 * sn);
}

// ------------------------------------------------------------ flash attention
// R9-exact config (best measured ~114us, reproduced twice): 1024 x 256-thread
// blocks (4 waves, 32 q-rows each), ring-4 pipelined K/V with counted vmcnt(4)
// (T4: never drain to 0 in the main loop), cross-iter QK^T, (256,2), XCD swizzle.
// R18's fused Q-norm/rope variant regressed (+35us): 32 sincosf/thread of VALU
// cannot hide in a 2-blocks/CU latency-bound kernel — norm/rope stays standalone.
__global__ __launch_bounds__(256, 2) void attn_kernel(const unsigned short* __restrict__ Q,
                                                      const unsigned short* __restrict__ Kb,
                                                      const unsigned short* __restrict__ Vtl,
                                                      unsigned short* __restrict__ O) {
  __shared__ unsigned short lds[32768];   // 64 KiB: K rings [0,16384), V rings [16384,32768)
  __shared__ float cl[4][32];
  const int t = threadIdx.x, l = t & 63, w = t >> 6;
  const int lq = l & 31, hi = l >> 5;
  const int orig = blockIdx.x;
  const int blk = (orig & 7) * 128 + (orig >> 3);   // XCD swizzle (1024 % 8 == 0)
  const int qb = blk & 7, h = (blk >> 3) & 31, b = blk >> 8;
  const int kv = h >> 2;                     // GQA: 4 q-heads per kv-head
  const int q0 = qb * 128 + w * 32;

  // Q as B-fragments, (1/sqrt(128))*log2(e) folded in
  const float qsc = 0.12751791438584222f;
  bf16x8 qf[8];
  const unsigned short* qrow = Q + (long)(b * SEQ + q0 + lq) * HID + h * HDIM + 8 * hi;
#pragma unroll
  for (int ks = 0; ks < 8; ++ks) {
    u16x8 raw = *(const u16x8*)(qrow + ks * 16);
    bf16x8 qv;
#pragma unroll
    for (int j = 0; j < 8; ++j) qv[j] = (__bf16)(bf2f(raw[j]) * qsc);
    qf[ks] = qv;
  }

  const unsigned short* Kg = Kb + (long)(b * SEQ) * 1024 + kv * HDIM;
  const unsigned short* Vg = Vtl + (long)(b * NKV + kv) * 32 * 4096;

  // stage: 8KB/tile each for K and V; 256 threads x 2 gload16 each.
#define STG_K(ring, ti) do { \
    _Pragma("unroll") for (int rr = 0; rr < 2; ++rr) { \
      int _row = (rr * 4 + w) * 4 + (l >> 4); \
      int _sc  = (l & 15) ^ (_row & 15); \
      gload16(Kg + (long)((ti) * 32 + _row) * 1024 + (_sc << 3), \
              lds + (ring) * 4096 + (rr * 4 + w) * 512); \
    } } while (0)
#define STG_V(ring, ti) do { \
    _Pragma("unroll") for (int rr = 0; rr < 2; ++rr) \
      gload16(Vg + (long)(ti) * 4096 + (((rr * 4 + w) * 64 + l) << 3), \
              lds + 16384 + (ring) * 4096 + (rr * 4 + w) * 512); \
    } while (0)
#define QKT(dst, ring) do { \
    const unsigned short* kb = lds + (ring) * 4096 + lq * 128; \
    bf16x8 kf[8]; \
    _Pragma("unroll") for (int ks = 0; ks < 8; ++ks) \
      kf[ks] = *(const bf16x8*)(kb + ((((ks << 1) + hi) ^ (lq & 15)) << 3)); \
    __builtin_amdgcn_s_setprio(1); \
    _Pragma("unroll") for (int ks = 0; ks < 8; ++ks) \
      dst = __builtin_amdgcn_mfma_f32_32x32x16_bf16(kf[ks], qf[ks], dst, 0, 0, 0); \
    __builtin_amdgcn_s_setprio(0); \
  } while (0)

  f32x16 acc[4] = {};
  float m = -3.0e38f, lsum = 0.f;

  // prologue: tiles 0,1,2 into rings 0,1,2; tile0 landed -> QK(0)
  STG_K(0, 0); STG_V(0, 0);
  STG_K(1, 1); STG_V(1, 1);
  STG_K(2, 2); STG_V(2, 2);
  asm volatile("s_waitcnt vmcnt(8)" ::: "memory");
  __builtin_amdgcn_s_barrier();
  __builtin_amdgcn_sched_barrier(0);

  f32x16 s_cur = {};
  QKT(s_cur, 0);

#pragma unroll 2
  for (int ti = 0; ti < 32; ++ti) {
    asm volatile("s_waitcnt vmcnt(4)" ::: "memory");
    __builtin_amdgcn_s_barrier();
    __builtin_amdgcn_sched_barrier(0);

    const int rs = (ti + 3) & 3, tn = (ti + 3) & 31;
    STG_K(rs, tn); STG_V(rs, tn);

    // QK^T of NEXT tile (independent of softmax below)
    f32x16 s_next = {};
    QKT(s_next, (ti + 1) & 3);

    // online softmax on s_cur (tile ti)
    float t0 = fmaxf(fmaxf(s_cur[0], s_cur[1]), fmaxf(s_cur[2], s_cur[3]));
    float t1 = fmaxf(fmaxf(s_cur[4], s_cur[5]), fmaxf(s_cur[6], s_cur[7]));
    float t2 = fmaxf(fmaxf(s_cur[8], s_cur[9]), fmaxf(s_cur[10], s_cur[11]));
    float t3 = fmaxf(fmaxf(s_cur[12], s_cur[13]), fmaxf(s_cur[14], s_cur[15]));
    float rm = fmaxf(fmaxf(t0, t1), fmaxf(t2, t3));
    rm = fmaxf(rm, __shfl_xor(rm, 32, 64));

    if (__any(rm > m + 8.0f)) {        // T13 defer-max
      float mn = fmaxf(m, rm);
      float corr = exp2f(m - mn);
      m = mn;
      lsum *= corr;
      cl[w][lq] = corr;
      float cc[16];
#pragma unroll
      for (int r = 0; r < 16; ++r)
        cc[r] = cl[w][(r & 3) + 8 * (r >> 2) + 4 * hi];
#pragma unroll
      for (int db = 0; db < 4; ++db)
#pragma unroll
        for (int r = 0; r < 16; ++r) acc[db][r] *= cc[r];
    }

    float p[16];
    float ps = 0.f;
#pragma unroll
    for (int r = 0; r < 16; ++r) { p[r] = exp2f(s_cur[r] - m); ps += p[r]; }
    lsum += ps + __shfl_xor(ps, 32, 64);

    // T12: pack P into PV A-fragments
    bf16x8 pa[2];
#pragma unroll
    for (int c = 0; c < 2; ++c) {
      unsigned a0 = cvtpk_bf16(p[8 * c + 0], p[8 * c + 1]);
      unsigned b0 = cvtpk_bf16(p[8 * c + 4], p[8 * c + 5]);
      unsigned a1 = cvtpk_bf16(p[8 * c + 2], p[8 * c + 3]);
      unsigned b1 = cvtpk_bf16(p[8 * c + 6], p[8 * c + 7]);
      asm("v_permlane32_swap_b32 %0, %1" : "+v"(a0), "+v"(b0));
      asm("v_permlane32_swap_b32 %0, %1" : "+v"(a1), "+v"(b1));
      u32x4 w4 = {a0, a1, b0, b1};
      pa[c] = __builtin_bit_cast(bf16x8, w4);
    }

    // PV from V ring ti&3 (swizzled [d][k32] tile)
    __builtin_amdgcn_s_setprio(1);
#pragma unroll
    for (int db = 0; db < 4; ++db) {
      const int row = db * 32 + lq;
      const int fx  = (row ^ (row >> 2)) & 3;
      const unsigned short* vb = lds + 16384 + (ti & 3) * 4096 + row * 32;
      bf16x8 v0 = *(const bf16x8*)(vb + ((hi ^ fx) << 3));
      bf16x8 v1 = *(const bf16x8*)(vb + (((2 + hi) ^ fx) << 3));
      acc[db] = __builtin_amdgcn_mfma_f32_32x32x16_bf16(pa[0], v0, acc[db], 0, 0, 0);
      acc[db] = __builtin_amdgcn_mfma_f32_32x32x16_bf16(pa[1], v1, acc[db], 0, 0, 0);
    }
    __builtin_amdgcn_s_setprio(0);

    s_cur = s_next;
  }
#undef STG_K
#undef STG_V
#undef QKT

  float il = 1.0f / lsum;
  cl[w][lq] = il;
  float ic[16];
#pragma unroll
  for (int r = 0; r < 16; ++r)
    ic[r] = cl[w][(r & 3) + 8 * (r >> 2) + 4 * hi];
#pragma unroll
  for (int db = 0; db < 4; ++db)
#pragma unroll
    for (int r = 0; r < 16; ++r) {
      int row = (r & 3) + 8 * (r >> 2) + 4 * hi;
      O[(long)(b * SEQ + q0 + row) * HID + h * HDIM + db * 32 + lq] =
          f2bf(acc[db][r] * ic[r]);
    }
}

// ------------------------------------------------------------------- launcher
extern "C" void kernel_launch(void* const* d_in, const int* in_sizes, int n_in,
                              void* d_out, int out_size, void* d_ws, size_t ws_size,
                              hipStream_t stream) {
  (void)in_sizes; (void)n_in; (void)out_size; (void)ws_size;
  const int*   positions = (const int*)d_in[0];
  const float* hs = (const float*)d_in[1];
  const float* wq = (const float*)d_in[2];
  const float* wk = (const float*)d_in[3];
  const float* wv = (const float*)d_in[4];
  const float* wo = (const float*)d_in[5];
  const float* qw = (const float*)d_in[6];
  const float* kw = (const float*)d_in[7];

  char* ws = (char*)d_ws;                                   // 160 MB total
  unsigned short* hs_b = (unsigned short*)(ws);              // 32 MB
  unsigned short* wq_b = (unsigned short*)(ws + 33554432);   // 32 MB (reused as attn-out)
  unsigned short* wk_b = (unsigned short*)(ws + 67108864);   //  8 MB
  unsigned short* wv_b = (unsigned short*)(ws + 75497472);   //  8 MB
  unsigned short* wo_b = (unsigned short*)(ws + 83886080);   // 32 MB
  unsigned short* q_b  = (unsigned short*)(ws + 117440512);  // 32 MB
  unsigned short* k_b  = (unsigned short*)(ws + 150994944);  //  8 MB
  unsigned short* vt_b = (unsigned short*)(ws + 159383552);  //  8 MB (V tiles)
  unsigned short* ao_b = wq_b;  // wq dead after Q-proj; alias for attention out

  // fused f32 -> bf16 conversion (5 segments, one launch)
  cvt_all<<<dim3(28672), dim3(256), 0, stream>>>(hs, wq, wk, wv, wo,
                                                 hs_b, wq_b, wk_b, wv_b, wo_b);

  // Q-proj (8-phase 256²) then fused K+V proj (z-indexed)
  gemm8_bt<0><<<dim3(256), dim3(512), 0, stream>>>(hs_b, wq_b, q_b);
  gemm_kv<<<dim3(32, 8, 2), dim3(256), 0, stream>>>(hs_b, wk_b, wv_b, k_b, vt_b);

  // fused per-head RMSNorm + RoPE for Q and K (one launch)
  normrope_all<<<dim3(40960), dim3(256), 0, stream>>>(q_b, k_b, qw, kw, positions);

  // attention: 1024 x 256-thread blocks, ring-4 pipelined K/V (R9 config)
  attn_kernel<<<dim3(1024), dim3(256), 0, stream>>>(q_b, k_b, vt_b, ao_b);

  // output projection -> f32 d_out (8-phase 256² template)
  gemm8_bt<1><<<dim3(256), dim3(512), 0, stream>>>(ao_b, wo_b, (float*)d_out);
}